// Round 19
// baseline (3622.538 us; speedup 1.0000x reference)
//
#include <hip/hip_runtime.h>
#include <hip/hip_bf16.h>
#include <stdint.h>

// Problem dims
#define N_ 64
#define T_ 256
#define K_ 4

#define DL 300
#define HL 300
#define H4L 1200
#define DA 88
#define HA 64
#define H4A 256
#define DI 128
#define HI 128
#define H4I 512
// K-dims padded to multiples of 32 for prepacked bf16 weights
#define DLP 320
#define DAP 96
#define DIP 128

typedef __hip_bfloat16 bf16;
typedef __attribute__((ext_vector_type(8))) short bf16x8;
typedef __attribute__((ext_vector_type(4))) float f32x4;

__device__ __forceinline__ float sigf(float x) { return 1.0f / (1.0f + expf(-x)); }

__device__ __forceinline__ unsigned pk2(float lo, float hi) {
    bf16 a = __float2bfloat16(lo), b = __float2bfloat16(hi);
    return (unsigned)*(unsigned short*)&a | ((unsigned)*(unsigned short*)&b << 16);
}
__device__ __forceinline__ float uplo(unsigned u) { return __uint_as_float(u << 16); }
__device__ __forceinline__ float uphi(unsigned u) { return __uint_as_float(u & 0xFFFF0000u); }

// Mask dtype detected at runtime: 0 = int32, 1 = uint8, 2 = float32.
__device__ __forceinline__ int read_mask(const void* m, size_t idx, int mode) {
    if (mode == 0) return ((const int*)m)[idx];
    if (mode == 1) return (int)((const unsigned char*)m)[idx];
    return ((const float*)m)[idx] != 0.0f;
}

__global__ void mask_mode_detect(const unsigned int* __restrict__ m, int* __restrict__ modep) {
    __shared__ unsigned int f[2];
    if (threadIdx.x == 0) { f[0] = 0u; f[1] = 0u; }
    __syncthreads();
    unsigned int gt1 = 0, f32one = 0;
    for (int i = threadIdx.x; i < 4096; i += 256) {
        const unsigned int v = m[i];
        if (v > 1u) gt1 = 1u;
        if (v == 0x3F800000u) f32one = 1u;
    }
    if (gt1) atomicOr(&f[0], 1u);
    if (f32one) atomicOr(&f[1], 1u);
    __syncthreads();
    if (threadIdx.x == 0) modep[0] = f[0] ? (f[1] ? 2 : 1) : 0;
}

// One-time prepack of Wih -> bf16, rows padded to 32-multiple K.
__global__ void prep_w3(const float* __restrict__ WL, const float* __restrict__ WA,
                        const float* __restrict__ WI,
                        unsigned short* __restrict__ pL, unsigned short* __restrict__ pA,
                        unsigned short* __restrict__ pI)
{
    const int i = blockIdx.x * 256 + threadIdx.x;
    if (i < H4L * DLP) {
        const int r = i / DLP, d = i - r * DLP;
        bf16 v = __float2bfloat16(d < DL ? WL[(size_t)r * DL + d] : 0.0f);
        pL[i] = *(unsigned short*)&v;
    }
    if (i < H4A * DAP) {
        const int r = i / DAP, d = i - r * DAP;
        bf16 v = __float2bfloat16(d < DA ? WA[(size_t)r * DA + d] : 0.0f);
        pA[i] = *(unsigned short*)&v;
    }
    if (i < H4I * DIP) {
        const int r = i / DIP, d = i - r * DIP;
        bf16 v = __float2bfloat16(WI[(size_t)r * DI + d]);
        pI[i] = *(unsigned short*)&v;
    }
}

// One-time prepack of Whh -> packed bf16 pairs [row][col/2] (u32).
__global__ void prep_whh(const float* __restrict__ WL, const float* __restrict__ WA,
                         const float* __restrict__ WI,
                         unsigned* __restrict__ pL, unsigned* __restrict__ pA,
                         unsigned* __restrict__ pI)
{
    const int i = blockIdx.x * 256 + threadIdx.x;
    if (i < 1200 * 150) {
        const int r = i / 150, c = i - r * 150;
        pL[i] = pk2(WL[(size_t)r * 300 + 2 * c], WL[(size_t)r * 300 + 2 * c + 1]);
    }
    if (i < 256 * 32) {
        const int r = i / 32, c = i - r * 32;
        pA[i] = pk2(WA[(size_t)r * 64 + 2 * c], WA[(size_t)r * 64 + 2 * c + 1]);
    }
    if (i < 512 * 64) {
        const int r = i / 64, c = i - r * 64;
        pI[i] = pk2(WI[(size_t)r * 128 + 2 * c], WI[(size_t)r * 128 + 2 * c + 1]);
    }
}

// Fusion head collapse: w = W2@W1 (492 weights), c0 = W2.b1 + b2 (wbuf[500]).
__global__ void wprep(const float* __restrict__ W1, const float* __restrict__ b1,
                      const float* __restrict__ W2, const float* __restrict__ b2,
                      float* __restrict__ wbuf)
{
    const int j = threadIdx.x;
    if (j < 492) {
        float a = 0.0f;
        for (int r = 0; r < 256; ++r) a += W2[r] * W1[r * 492 + j];
        wbuf[j] = a;
    } else if (j == 492) {
        float a = 0.0f;
        for (int r = 0; r < 256; ++r) a += W2[r] * b1[r];
        wbuf[500] = a + b2[0];
    }
}

// ---------------------------------------------------------------------------
// Merged xproj GEMM (MFMA bf16), blockIdx.z = modality. W prepacked bf16.
// ---------------------------------------------------------------------------
__global__ __launch_bounds__(256) void gemm_xz3(
    const float* __restrict__ XL, const unsigned short* __restrict__ WL,
    const float* __restrict__ biL, const float* __restrict__ bhL, bf16* __restrict__ ZL,
    const float* __restrict__ XA, const unsigned short* __restrict__ WA,
    const float* __restrict__ biA, const float* __restrict__ bhA, bf16* __restrict__ ZA,
    const float* __restrict__ XI, const unsigned short* __restrict__ WI,
    const float* __restrict__ biI, const float* __restrict__ bhI, bf16* __restrict__ ZI,
    const int* __restrict__ seqlen, int Tc, int t0)
{
    __shared__ __align__(16) unsigned short Xs[64 * 40];
    __shared__ __align__(16) unsigned short Ws[64 * 40];
    const int z = blockIdx.z;
    const float* X; const unsigned short* W; const float* bih; const float* bhh; bf16* XZ;
    int D, Dp, H4;
    if (z == 0)      { X = XL; W = WL; bih = biL; bhh = bhL; XZ = ZL; D = DL; Dp = DLP; H4 = H4L; }
    else if (z == 1) { X = XA; W = WA; bih = biA; bhh = bhA; XZ = ZA; D = DA; Dp = DAP; H4 = H4A; }
    else             { X = XI; W = WI; bih = biI; bhh = bhI; XZ = ZI; D = DI; Dp = DIP; H4 = H4I; }

    const int j0 = blockIdx.x * 64;
    if (j0 >= H4) return;

    const int tid = threadIdx.x;
    const int m0 = blockIdx.y * 64;
    const int Tc4 = Tc * 4;

    int act = 0;
    if (tid < 64) {
        const int rr = m0 + tid;
        const int n = rr / Tc4;
        const int ttt = (rr % Tc4) >> 2;
        act = (t0 + ttt) < seqlen[n];
    }
    if (!__syncthreads_or(act)) return;

    const int srow = tid >> 2;
    const int sq = tid & 3;
    const int rr = m0 + srow;
    const int n = rr / Tc4;
    const int ttt = (rr % Tc4) >> 2;
    const int kk_ = rr & 3;
    const float* xrow = X + ((size_t)((n * T_ + t0 + ttt) * 4 + kk_)) * D;
    const int wcol = j0 + srow;
    const bool wvalid = wcol < H4;
    const unsigned short* wrow = W + (size_t)(wvalid ? wcol : 0) * Dp;

    const int lane = tid & 63;
    const int wv = tid >> 6;
    const int fr = lane & 15;
    const int fk = (lane >> 4) * 8;

    f32x4 acc[4] = {{0,0,0,0},{0,0,0,0},{0,0,0,0},{0,0,0,0}};

    const int nks = Dp >> 5;
    for (int ks = 0; ks < nks; ++ks) {
        const int d0 = ks * 32 + sq * 8;
        float xf[8];
        if (d0 + 7 < D) {
            const float4 a0 = *(const float4*)(xrow + d0);
            const float4 a1 = *(const float4*)(xrow + d0 + 4);
            xf[0]=a0.x; xf[1]=a0.y; xf[2]=a0.z; xf[3]=a0.w;
            xf[4]=a1.x; xf[5]=a1.y; xf[6]=a1.z; xf[7]=a1.w;
        } else {
#pragma unroll
            for (int e = 0; e < 8; ++e) {
                const int d = d0 + e;
                xf[e] = (d < D) ? xrow[d] : 0.0f;
            }
        }
        union { unsigned short u[8]; uint4 v; } px;
#pragma unroll
        for (int e = 0; e < 8; ++e) {
            bf16 hx = __float2bfloat16(xf[e]);
            px.u[e] = *(unsigned short*)&hx;
        }
        uint4 pwv = make_uint4(0u, 0u, 0u, 0u);
        if (wvalid) pwv = *(const uint4*)&wrow[d0];
        __syncthreads();
        *(uint4*)&Xs[srow * 40 + sq * 8] = px.v;
        *(uint4*)&Ws[srow * 40 + sq * 8] = pwv;
        __syncthreads();
        const bf16x8 a = *(const bf16x8*)&Xs[(wv * 16 + fr) * 40 + fk];
#pragma unroll
        for (int c = 0; c < 4; ++c) {
            const bf16x8 b = *(const bf16x8*)&Ws[(c * 16 + fr) * 40 + fk];
            acc[c] = __builtin_amdgcn_mfma_f32_16x16x32_bf16(a, b, acc[c], 0, 0, 0);
        }
    }
#pragma unroll
    for (int c = 0; c < 4; ++c) {
        const int col = j0 + c * 16 + fr;
        if (col < H4) {
            const float bias = bih[col] + bhh[col];
#pragma unroll
            for (int rg = 0; rg < 4; ++rg) {
                const int row = m0 + wv * 16 + (lane >> 4) * 4 + rg;
                XZ[(size_t)row * H4 + col] = __float2bfloat16(acc[c][rg] + bias);
            }
        }
    }
}

// ---------------------------------------------------------------------------
// Merged recurrence. ROUND-19 changes to the ling inner round (critical path):
//  (1) reduce+update merged: the 75 update threads gather their 4 gate rows
//      directly from zp_s (removes zr_s staging + one 512-thr barrier; 5->4).
//  (2) xz prefetched BEFORE the matvec (no h dependency) -> global latency
//      hides under the FMA chain.
//  (3) own-slice write-through: block writes its 75 h into h_s locally and
//      reads back only the 225 remote values; mask bits hoisted per t.
// Flag protocol identical to round 18 (per-block release flags, depth-2
// parity buffer, siblings share control flow).
// ---------------------------------------------------------------------------
__global__ __launch_bounds__(512, 1) void recur_all(
    const unsigned* __restrict__ WpkL, const unsigned* __restrict__ WpkA,
    const unsigned* __restrict__ WpkI,
    const void* __restrict__ mL, const void* __restrict__ mA, const void* __restrict__ mI,
    const int* __restrict__ modep,
    const int* __restrict__ seqlen,
    const float* __restrict__ wbuf,
    const bf16* __restrict__ xzL, const bf16* __restrict__ xzA, const bf16* __restrict__ xzI,
    float* __restrict__ psumL, float* __restrict__ psumA, float* __restrict__ psumI,
    float* __restrict__ hcL, float* __restrict__ hcA, float* __restrict__ hcI,
    float* __restrict__ hpub,       // [N][2][304]
    unsigned int* __restrict__ flg, // [N][8] slice for THIS chunk, pre-zeroed
    int Tc, int t0)
{
    // ling LDS
    __shared__ float h_s[304];
    __shared__ float c_s[80];
    __shared__ float zp_s[8 * 308];
    __shared__ float wb_s[304];
    // small LDS
    __shared__ __align__(16) float h2_s[128];
    __shared__ __align__(16) float c2_s[128];
    __shared__ __align__(16) float z2_s[512];
    __shared__ float wb2_s[128];
    const int tid = threadIdx.x;
    const int mode = modep[0];

    if (blockIdx.x < 4 * N_) {
        // ================= linguistic =================
        const int xcd = blockIdx.x & 7;
        const int idx = blockIdx.x >> 3;
        const int n = xcd * 8 + (idx >> 2);
        const int b = idx & 3;
        const int hb = 75 * b;
        const int seqn = seqlen[n];

        const int chunk = tid & 7;
        const int rb = tid >> 3;
        const int cjp = chunk * 19;     // packed-col base (19 u32 = 38 cols)
        unsigned w[5][19];
#pragma unroll
        for (int s = 0; s < 5; ++s) {
            const int lr = rb + 64 * s;
            const bool rv = (lr < 300);
            const int gl = rv ? (lr / 75) : 0;
            const int i  = rv ? (lr - gl * 75) : 0;
            const unsigned* wp = WpkL + ((size_t)(gl * 300 + hb + i)) * 150 + cjp;
#pragma unroll
            for (int j = 0; j < 19; ++j) w[s][j] = rv ? wp[j] : 0u;
        }
        for (int r = tid; r < 304; r += 512) {
            if (t0 == 0 || r >= 300) h_s[r] = 0.0f;
            else h_s[r] = hcL[n * 600 + r];
            wb_s[r] = (r < 300) ? wbuf[r] : 0.0f;
        }
        if (tid < 75) c_s[tid] = (t0 == 0) ? 0.0f : hcL[n * 600 + 300 + hb + tid];
        __syncthreads();

        unsigned int serial = 0;
        unsigned int* const flgn = &flg[n * 8];
        float* const hp = hpub + (size_t)n * 608;

#pragma unroll 1
        for (int tt = 0; tt < Tc; ++tt) {
            const int t = t0 + tt;
            if (t >= seqn) {
                if (b == 0 && tid == 0) psumL[(size_t)n * T_ + t] = 0.0f;
                continue;
            }
            const size_t mbase = (size_t)(n * T_ + t) * 4;
            int mk0 = read_mask(mL, mbase + 0, mode);
            int mk1 = read_mask(mL, mbase + 1, mode);
            int mk2 = read_mask(mL, mbase + 2, mode);
            int mk3 = read_mask(mL, mbase + 3, mode);
            const bf16* xzt = xzL + ((size_t)((n * Tc + tt) * 4)) * 1200;
#pragma unroll 1
            for (int k = 0; k < 4; ++k) {
                const int mk = (k == 0) ? mk0 : (k == 1) ? mk1 : (k == 2) ? mk2 : mk3;
                if (!mk) continue;
                const int par = (int)(serial & 1u);
                // xz prefetch: 4 gate values per update thread, issued pre-matvec
                float xzv0 = 0.f, xzv1 = 0.f, xzv2 = 0.f, xzv3 = 0.f;
                if (tid < 75) {
                    const bf16* xb = xzt + k * 1200 + hb + tid;
                    xzv0 = __bfloat162float(xb[0]);
                    xzv1 = __bfloat162float(xb[300]);
                    xzv2 = __bfloat162float(xb[600]);
                    xzv3 = __bfloat162float(xb[900]);
                }
                float a0 = 0.f, a1 = 0.f, a2 = 0.f, a3 = 0.f, a4 = 0.f;
#pragma unroll
                for (int j = 0; j < 19; ++j) {
                    const float2 hv = *(const float2*)&h_s[2 * (cjp + j)];
                    const unsigned u0 = w[0][j], u1 = w[1][j], u2 = w[2][j],
                                   u3 = w[3][j], u4 = w[4][j];
                    a0 += uplo(u0) * hv.x + uphi(u0) * hv.y;
                    a1 += uplo(u1) * hv.x + uphi(u1) * hv.y;
                    a2 += uplo(u2) * hv.x + uphi(u2) * hv.y;
                    a3 += uplo(u3) * hv.x + uphi(u3) * hv.y;
                    a4 += uplo(u4) * hv.x + uphi(u4) * hv.y;
                }
                zp_s[chunk * 308 + rb]       = a0;
                zp_s[chunk * 308 + rb + 64]  = a1;
                zp_s[chunk * 308 + rb + 128] = a2;
                zp_s[chunk * 308 + rb + 192] = a3;
                if (rb < 44) zp_s[chunk * 308 + rb + 256] = a4;
                __syncthreads();   // B1: zp ready
                if (tid < 75) {
                    // merged reduce + gate update (gate g local rows g*75+tid)
                    float zi = xzv0, zf = xzv1, zg = xzv2, zo = xzv3;
#pragma unroll
                    for (int c = 0; c < 8; ++c) {
                        const float* zc = &zp_s[c * 308];
                        zi += zc[tid];
                        zf += zc[75 + tid];
                        zg += zc[150 + tid];
                        zo += zc[225 + tid];
                    }
                    const float cc = sigf(zf) * c_s[tid] + sigf(zi) * tanhf(zg);
                    c_s[tid] = cc;
                    const float hh = sigf(zo) * tanhf(cc);
                    h_s[hb + tid] = hh;    // local write-through
                    __hip_atomic_store(&hp[par * 304 + hb + tid], hh,
                                       __ATOMIC_RELAXED, __HIP_MEMORY_SCOPE_AGENT);
                }
                __syncthreads();   // B2: publishes + local writes drained
                if (tid == 0)
                    __hip_atomic_store(&flgn[b], serial + 1u,
                                       __ATOMIC_RELEASE, __HIP_MEMORY_SCOPE_AGENT);
                if (tid < 4) {     // poll sibling flags (coalesced)
                    long g = 0;
                    while (__hip_atomic_load(&flgn[tid], __ATOMIC_ACQUIRE,
                                             __HIP_MEMORY_SCOPE_AGENT) < serial + 1u
                           && g < (1L << 22)) { __builtin_amdgcn_s_sleep(1); ++g; }
                }
                __syncthreads();   // B3: all siblings published
                if (tid < 300 && (tid < hb || tid >= hb + 75))
                    h_s[tid] = __hip_atomic_load(&hp[par * 304 + tid],
                                                 __ATOMIC_RELAXED, __HIP_MEMORY_SCOPE_AGENT);
                __syncthreads();   // B4: h_s complete
                ++serial;
            }
            // fused projection: psumL[n][t] = wbuf[0:300] . h  (fp32)
            if (b == 0 && tid < 64) {
                float v = 0.0f;
                for (int r = tid; r < 300; r += 64) v += wb_s[r] * h_s[r];
#pragma unroll
                for (int off = 32; off; off >>= 1) v += __shfl_down(v, off, 64);
                if (tid == 0) psumL[(size_t)n * T_ + t] = v;
            }
        }
        if (tid < 75) {
            hcL[n * 600 + hb + tid] = h_s[hb + tid];
            hcL[n * 600 + 300 + hb + tid] = c_s[tid];
        }
    } else if (blockIdx.x < 4 * N_ + N_) {
        // ================= image =================
        const int n = blockIdx.x - 4 * N_;
        const int seqn = seqlen[n];
        unsigned w[64];
        {
            const uint4* wp = (const uint4*)(WpkI + (size_t)tid * 64);
#pragma unroll
            for (int jj = 0; jj < 16; ++jj) {
                const uint4 v = wp[jj];
                w[4 * jj] = v.x; w[4 * jj + 1] = v.y; w[4 * jj + 2] = v.z; w[4 * jj + 3] = v.w;
            }
        }
        if (tid < 128) {
            if (t0 == 0) { h2_s[tid] = 0.0f; c2_s[tid] = 0.0f; }
            else { h2_s[tid] = hcI[n * 256 + tid]; c2_s[tid] = hcI[n * 256 + 128 + tid]; }
            wb2_s[tid] = wbuf[364 + tid];
        }
        __syncthreads();
#pragma unroll 1
        for (int tt = 0; tt < Tc; ++tt) {
            const int t = t0 + tt;
            if (t >= seqn) {
                if (tid == 0) psumI[(size_t)n * T_ + t] = 0.0f;
                continue;
            }
            const size_t xbase = ((size_t)((n * Tc + tt) * 4)) * 512;
            const size_t mbase = (size_t)(n * T_ + t) * 4;
#pragma unroll 1
            for (int k = 0; k < 4; ++k) {
                if (!read_mask(mI, mbase + k, mode)) continue;
                float acc = __bfloat162float(xzI[xbase + k * 512 + tid]);
                const float2* hp2 = (const float2*)h2_s;
#pragma unroll
                for (int jj = 0; jj < 64; ++jj) {
                    const float2 hv = hp2[jj];
                    const unsigned u = w[jj];
                    acc += uplo(u) * hv.x + uphi(u) * hv.y;
                }
                z2_s[tid] = acc;
                __syncthreads();
                if (tid < 128) {
                    const float zi = z2_s[tid], zf = z2_s[128 + tid];
                    const float zg = z2_s[256 + tid], zo = z2_s[384 + tid];
                    const float cc = sigf(zf) * c2_s[tid] + sigf(zi) * tanhf(zg);
                    c2_s[tid] = cc;
                    h2_s[tid] = sigf(zo) * tanhf(cc);
                }
                __syncthreads();
            }
            if (tid < 64) {
                float v = wb2_s[tid] * h2_s[tid] + wb2_s[tid + 64] * h2_s[tid + 64];
#pragma unroll
                for (int off = 32; off; off >>= 1) v += __shfl_down(v, off, 64);
                if (tid == 0) psumI[(size_t)n * T_ + t] = v;
            }
        }
        if (tid < 128) { hcI[n * 256 + tid] = h2_s[tid]; hcI[n * 256 + 128 + tid] = c2_s[tid]; }
    } else {
        // ================= acoustic =================
        const int n = blockIdx.x - 5 * N_;
        const int seqn = seqlen[n];
        unsigned w[32];
        if (tid < 256) {
            const uint4* wp = (const uint4*)(WpkA + (size_t)tid * 32);
#pragma unroll
            for (int jj = 0; jj < 8; ++jj) {
                const uint4 v = wp[jj];
                w[4 * jj] = v.x; w[4 * jj + 1] = v.y; w[4 * jj + 2] = v.z; w[4 * jj + 3] = v.w;
            }
        }
        if (tid < 64) {
            if (t0 == 0) { h2_s[tid] = 0.0f; c2_s[tid] = 0.0f; }
            else { h2_s[tid] = hcA[n * 128 + tid]; c2_s[tid] = hcA[n * 128 + 64 + tid]; }
            wb2_s[tid] = wbuf[300 + tid];
        }
        __syncthreads();
#pragma unroll 1
        for (int tt = 0; tt < Tc; ++tt) {
            const int t = t0 + tt;
            if (t >= seqn) {
                if (tid == 0) psumA[(size_t)n * T_ + t] = 0.0f;
                continue;
            }
            const size_t xbase = ((size_t)((n * Tc + tt) * 4)) * 256;
            const size_t mbase = (size_t)(n * T_ + t) * 4;
#pragma unroll 1
            for (int k = 0; k < 4; ++k) {
                if (!read_mask(mA, mbase + k, mode)) continue;
                if (tid < 256) {
                    float acc = __bfloat162float(xzA[xbase + k * 256 + tid]);
                    const float2* hp2 = (const float2*)h2_s;
#pragma unroll
                    for (int jj = 0; jj < 32; ++jj) {
                        const float2 hv = hp2[jj];
                        const unsigned u = w[jj];
                        acc += uplo(u) * hv.x + uphi(u) * hv.y;
                    }
                    z2_s[tid] = acc;
                }
                __syncthreads();
                if (tid < 64) {
                    const float zi = z2_s[tid], zf = z2_s[64 + tid];
                    const float zg = z2_s[128 + tid], zo = z2_s[192 + tid];
                    const float cc = sigf(zf) * c2_s[tid] + sigf(zi) * tanhf(zg);
                    c2_s[tid] = cc;
                    h2_s[tid] = sigf(zo) * tanhf(cc);
                }
                __syncthreads();
            }
            if (tid < 64) {
                float v = wb2_s[tid] * h2_s[tid];
#pragma unroll
                for (int off = 32; off; off >>= 1) v += __shfl_down(v, off, 64);
                if (tid == 0) psumA[(size_t)n * T_ + t] = v;
            }
        }
        if (tid < 64) { hcA[n * 128 + tid] = h2_s[tid]; hcA[n * 128 + 64 + tid] = c2_s[tid]; }
    }
}

// Output: reshape-scramble gather of the three projected scalars.
// fused[i,j] = hs_scan[i*4 + j//64, j%64] -> source (nn=j&63, tt=i*4+(j>>6)).
__global__ void out_combine(const float* __restrict__ wbuf,
                            const float* __restrict__ pL, const float* __restrict__ pA,
                            const float* __restrict__ pI,
                            const float* __restrict__ lmask, float* __restrict__ out)
{
    const int i = blockIdx.x;
    const int j = threadIdx.x;
    const int nn = j & 63;
    const int tt = i * 4 + (j >> 6);
    const size_t src = (size_t)nn * T_ + tt;
    const size_t nt = (size_t)i * T_ + j;
    out[nt] = (pL[src] + pA[src] + pI[src] + wbuf[500]) * lmask[nt];
}

// ---------------------------------------------------------------------------
extern "C" void kernel_launch(void* const* d_in, const int* in_sizes, int n_in,
                              void* d_out, int out_size, void* d_ws, size_t ws_size,
                              hipStream_t stream)
{
    (void)in_sizes; (void)n_in;
    const float* xL   = (const float*)d_in[0];
    const void*  mL   = d_in[1];
    const float* WihL = (const float*)d_in[2];
    const float* WhhL = (const float*)d_in[3];
    const float* bihL = (const float*)d_in[4];
    const float* bhhL = (const float*)d_in[5];
    const float* xA   = (const float*)d_in[6];
    const void*  mA   = d_in[7];
    const float* WihA = (const float*)d_in[8];
    const float* WhhA = (const float*)d_in[9];
    const float* bihA = (const float*)d_in[10];
    const float* bhhA = (const float*)d_in[11];
    const float* xI   = (const float*)d_in[12];
    const void*  mI   = d_in[13];
    const float* WihI = (const float*)d_in[14];
    const float* WhhI = (const float*)d_in[15];
    const float* bihI = (const float*)d_in[16];
    const float* bhhI = (const float*)d_in[17];
    const int*   seqlen = (const int*)d_in[18];
    const float* lmask  = (const float*)d_in[19];
    const float* W1 = (const float*)d_in[20];
    const float* b1 = (const float*)d_in[21];
    const float* W2 = (const float*)d_in[22];
    const float* b2 = (const float*)d_in[23];
    float* out = (float*)d_out;

    // Byte-accurate workspace layout, 64B aligned blocks.
    char* base = (char*)d_ws;
    size_t off = 0;
    auto take = [&](size_t bytes) -> char* {
        char* p = base + off;
        off += (bytes + 63) & ~(size_t)63;
        return p;
    };
    unsigned int* flg = (unsigned int*)take(64 * 512 * sizeof(unsigned int)); // per-chunk [N][8] slices
    int*   modep = (int*)take(64);
    float* wbuf  = (float*)take(512 * sizeof(float));
    float* hcL   = (float*)take((size_t)N_ * 2 * HL * sizeof(float));
    float* hcA   = (float*)take((size_t)N_ * 2 * HA * sizeof(float));
    float* hcI   = (float*)take((size_t)N_ * 2 * HI * sizeof(float));
    float* hpub  = (float*)take((size_t)N_ * 2 * 304 * sizeof(float));
    float* psumL = (float*)take((size_t)N_ * T_ * sizeof(float));
    float* psumA = (float*)take((size_t)N_ * T_ * sizeof(float));
    float* psumI = (float*)take((size_t)N_ * T_ * sizeof(float));
    unsigned short* wpkL = (unsigned short*)take((size_t)H4L * DLP * sizeof(unsigned short));
    unsigned short* wpkA = (unsigned short*)take((size_t)H4A * DAP * sizeof(unsigned short));
    unsigned short* wpkI = (unsigned short*)take((size_t)H4I * DIP * sizeof(unsigned short));
    unsigned* whpL = (unsigned*)take((size_t)1200 * 150 * sizeof(unsigned));
    unsigned* whpA = (unsigned*)take((size_t)256 * 32 * sizeof(unsigned));
    unsigned* whpI = (unsigned*)take((size_t)512 * 64 * sizeof(unsigned));

    // largest t-chunk whose bf16 xz buffers fit in the remaining workspace
    const size_t xz_per_tc = (size_t)N_ * K_ * (H4L + H4A + H4I) * sizeof(bf16);
    int Tc = T_;
    while (Tc > 1 && off + (size_t)Tc * xz_per_tc + 256 > ws_size) Tc >>= 1;
    if (off + (size_t)Tc * xz_per_tc + 256 > ws_size) {
        hipMemsetAsync(d_out, 0, (size_t)out_size * sizeof(float), stream);
        return;
    }
    if (Tc > 64) Tc = 64;   // flg slices sized for <=64 chunks
    bf16* xzL = (bf16*)take((size_t)N_ * Tc * K_ * H4L * sizeof(bf16));
    bf16* xzA = (bf16*)take((size_t)N_ * Tc * K_ * H4A * sizeof(bf16));
    bf16* xzI = (bf16*)take((size_t)N_ * Tc * K_ * H4I * sizeof(bf16));

    const int nchunks = T_ / Tc;
    hipMemsetAsync(flg, 0, (size_t)nchunks * 512 * sizeof(unsigned int), stream);
    mask_mode_detect<<<1, 256, 0, stream>>>((const unsigned int*)mL, modep);
    wprep<<<1, 512, 0, stream>>>(W1, b1, W2, b2, wbuf);
    prep_w3<<<(H4L * DLP + 255) / 256, 256, 0, stream>>>(WihL, WihA, WihI, wpkL, wpkA, wpkI);
    prep_whh<<<(1200 * 150 + 255) / 256, 256, 0, stream>>>(WhhL, WhhA, WhhI, whpL, whpA, whpI);

    const int My = (N_ * Tc * K_) / 64;
    for (int c = 0; c < nchunks; ++c) {
        const int t0 = c * Tc;
        gemm_xz3<<<dim3((H4L + 63) / 64, My, 3), 256, 0, stream>>>(
            xL, wpkL, bihL, bhhL, xzL,
            xA, wpkA, bihA, bhhA, xzA,
            xI, wpkI, bihI, bhhI, xzI,
            seqlen, Tc, t0);
        recur_all<<<6 * N_, 512, 0, stream>>>(
            whpL, whpA, whpI, mL, mA, mI, modep, seqlen, wbuf,
            xzL, xzA, xzI, psumL, psumA, psumI,
            hcL, hcA, hcI, hpub, flg + (size_t)c * 512, Tc, t0);
    }
    out_combine<<<N_, T_, 0, stream>>>(wbuf, psumL, psumA, psumI, lmask, out);
}

// Round 20
// 3252.647 us; speedup vs baseline: 1.1137x; 1.1137x over previous
//
#include <hip/hip_runtime.h>
#include <hip/hip_bf16.h>
#include <stdint.h>

// Problem dims
#define N_ 64
#define T_ 256
#define K_ 4

#define DL 300
#define HL 300
#define H4L 1200
#define DA 88
#define HA 64
#define H4A 256
#define DI 128
#define HI 128
#define H4I 512
// K-dims padded to multiples of 32 for prepacked bf16 weights
#define DLP 320
#define DAP 96
#define DIP 128

typedef __hip_bfloat16 bf16;
typedef __attribute__((ext_vector_type(8))) short bf16x8;
typedef __attribute__((ext_vector_type(4))) float f32x4;

__device__ __forceinline__ float sigf(float x) { return 1.0f / (1.0f + expf(-x)); }

__device__ __forceinline__ unsigned pk2(float lo, float hi) {
    bf16 a = __float2bfloat16(lo), b = __float2bfloat16(hi);
    return (unsigned)*(unsigned short*)&a | ((unsigned)*(unsigned short*)&b << 16);
}
__device__ __forceinline__ float uplo(unsigned u) { return __uint_as_float(u << 16); }
__device__ __forceinline__ float uphi(unsigned u) { return __uint_as_float(u & 0xFFFF0000u); }

// Mask dtype detected at runtime: 0 = int32, 1 = uint8, 2 = float32.
__device__ __forceinline__ int read_mask(const void* m, size_t idx, int mode) {
    if (mode == 0) return ((const int*)m)[idx];
    if (mode == 1) return (int)((const unsigned char*)m)[idx];
    return ((const float*)m)[idx] != 0.0f;
}

__global__ void mask_mode_detect(const unsigned int* __restrict__ m, int* __restrict__ modep) {
    __shared__ unsigned int f[2];
    if (threadIdx.x == 0) { f[0] = 0u; f[1] = 0u; }
    __syncthreads();
    unsigned int gt1 = 0, f32one = 0;
    for (int i = threadIdx.x; i < 4096; i += 256) {
        const unsigned int v = m[i];
        if (v > 1u) gt1 = 1u;
        if (v == 0x3F800000u) f32one = 1u;
    }
    if (gt1) atomicOr(&f[0], 1u);
    if (f32one) atomicOr(&f[1], 1u);
    __syncthreads();
    if (threadIdx.x == 0) modep[0] = f[0] ? (f[1] ? 2 : 1) : 0;
}

// One-time prepack of Wih -> bf16, rows padded to 32-multiple K.
__global__ void prep_w3(const float* __restrict__ WL, const float* __restrict__ WA,
                        const float* __restrict__ WI,
                        unsigned short* __restrict__ pL, unsigned short* __restrict__ pA,
                        unsigned short* __restrict__ pI)
{
    const int i = blockIdx.x * 256 + threadIdx.x;
    if (i < H4L * DLP) {
        const int r = i / DLP, d = i - r * DLP;
        bf16 v = __float2bfloat16(d < DL ? WL[(size_t)r * DL + d] : 0.0f);
        pL[i] = *(unsigned short*)&v;
    }
    if (i < H4A * DAP) {
        const int r = i / DAP, d = i - r * DAP;
        bf16 v = __float2bfloat16(d < DA ? WA[(size_t)r * DA + d] : 0.0f);
        pA[i] = *(unsigned short*)&v;
    }
    if (i < H4I * DIP) {
        const int r = i / DIP, d = i - r * DIP;
        bf16 v = __float2bfloat16(WI[(size_t)r * DI + d]);
        pI[i] = *(unsigned short*)&v;
    }
}

// One-time prepack of Whh -> packed bf16 pairs [row][col/2] (u32).
__global__ void prep_whh(const float* __restrict__ WL, const float* __restrict__ WA,
                         const float* __restrict__ WI,
                         unsigned* __restrict__ pL, unsigned* __restrict__ pA,
                         unsigned* __restrict__ pI)
{
    const int i = blockIdx.x * 256 + threadIdx.x;
    if (i < 1200 * 150) {
        const int r = i / 150, c = i - r * 150;
        pL[i] = pk2(WL[(size_t)r * 300 + 2 * c], WL[(size_t)r * 300 + 2 * c + 1]);
    }
    if (i < 256 * 32) {
        const int r = i / 32, c = i - r * 32;
        pA[i] = pk2(WA[(size_t)r * 64 + 2 * c], WA[(size_t)r * 64 + 2 * c + 1]);
    }
    if (i < 512 * 64) {
        const int r = i / 64, c = i - r * 64;
        pI[i] = pk2(WI[(size_t)r * 128 + 2 * c], WI[(size_t)r * 128 + 2 * c + 1]);
    }
}

// Fusion head collapse: w = W2@W1 (492 weights), c0 = W2.b1 + b2 (wbuf[500]).
__global__ void wprep(const float* __restrict__ W1, const float* __restrict__ b1,
                      const float* __restrict__ W2, const float* __restrict__ b2,
                      float* __restrict__ wbuf)
{
    const int j = threadIdx.x;
    if (j < 492) {
        float a = 0.0f;
        for (int r = 0; r < 256; ++r) a += W2[r] * W1[r * 492 + j];
        wbuf[j] = a;
    } else if (j == 492) {
        float a = 0.0f;
        for (int r = 0; r < 256; ++r) a += W2[r] * b1[r];
        wbuf[500] = a + b2[0];
    }
}

// ---------------------------------------------------------------------------
// Merged xproj GEMM (MFMA bf16), blockIdx.z = modality. W prepacked bf16.
// ---------------------------------------------------------------------------
__global__ __launch_bounds__(256) void gemm_xz3(
    const float* __restrict__ XL, const unsigned short* __restrict__ WL,
    const float* __restrict__ biL, const float* __restrict__ bhL, bf16* __restrict__ ZL,
    const float* __restrict__ XA, const unsigned short* __restrict__ WA,
    const float* __restrict__ biA, const float* __restrict__ bhA, bf16* __restrict__ ZA,
    const float* __restrict__ XI, const unsigned short* __restrict__ WI,
    const float* __restrict__ biI, const float* __restrict__ bhI, bf16* __restrict__ ZI,
    const int* __restrict__ seqlen, int Tc, int t0)
{
    __shared__ __align__(16) unsigned short Xs[64 * 40];
    __shared__ __align__(16) unsigned short Ws[64 * 40];
    const int z = blockIdx.z;
    const float* X; const unsigned short* W; const float* bih; const float* bhh; bf16* XZ;
    int D, Dp, H4;
    if (z == 0)      { X = XL; W = WL; bih = biL; bhh = bhL; XZ = ZL; D = DL; Dp = DLP; H4 = H4L; }
    else if (z == 1) { X = XA; W = WA; bih = biA; bhh = bhA; XZ = ZA; D = DA; Dp = DAP; H4 = H4A; }
    else             { X = XI; W = WI; bih = biI; bhh = bhI; XZ = ZI; D = DI; Dp = DIP; H4 = H4I; }

    const int j0 = blockIdx.x * 64;
    if (j0 >= H4) return;

    const int tid = threadIdx.x;
    const int m0 = blockIdx.y * 64;
    const int Tc4 = Tc * 4;

    int act = 0;
    if (tid < 64) {
        const int rr = m0 + tid;
        const int n = rr / Tc4;
        const int ttt = (rr % Tc4) >> 2;
        act = (t0 + ttt) < seqlen[n];
    }
    if (!__syncthreads_or(act)) return;

    const int srow = tid >> 2;
    const int sq = tid & 3;
    const int rr = m0 + srow;
    const int n = rr / Tc4;
    const int ttt = (rr % Tc4) >> 2;
    const int kk_ = rr & 3;
    const float* xrow = X + ((size_t)((n * T_ + t0 + ttt) * 4 + kk_)) * D;
    const int wcol = j0 + srow;
    const bool wvalid = wcol < H4;
    const unsigned short* wrow = W + (size_t)(wvalid ? wcol : 0) * Dp;

    const int lane = tid & 63;
    const int wv = tid >> 6;
    const int fr = lane & 15;
    const int fk = (lane >> 4) * 8;

    f32x4 acc[4] = {{0,0,0,0},{0,0,0,0},{0,0,0,0},{0,0,0,0}};

    const int nks = Dp >> 5;
    for (int ks = 0; ks < nks; ++ks) {
        const int d0 = ks * 32 + sq * 8;
        float xf[8];
        if (d0 + 7 < D) {
            const float4 a0 = *(const float4*)(xrow + d0);
            const float4 a1 = *(const float4*)(xrow + d0 + 4);
            xf[0]=a0.x; xf[1]=a0.y; xf[2]=a0.z; xf[3]=a0.w;
            xf[4]=a1.x; xf[5]=a1.y; xf[6]=a1.z; xf[7]=a1.w;
        } else {
#pragma unroll
            for (int e = 0; e < 8; ++e) {
                const int d = d0 + e;
                xf[e] = (d < D) ? xrow[d] : 0.0f;
            }
        }
        union { unsigned short u[8]; uint4 v; } px;
#pragma unroll
        for (int e = 0; e < 8; ++e) {
            bf16 hx = __float2bfloat16(xf[e]);
            px.u[e] = *(unsigned short*)&hx;
        }
        uint4 pwv = make_uint4(0u, 0u, 0u, 0u);
        if (wvalid) pwv = *(const uint4*)&wrow[d0];
        __syncthreads();
        *(uint4*)&Xs[srow * 40 + sq * 8] = px.v;
        *(uint4*)&Ws[srow * 40 + sq * 8] = pwv;
        __syncthreads();
        const bf16x8 a = *(const bf16x8*)&Xs[(wv * 16 + fr) * 40 + fk];
#pragma unroll
        for (int c = 0; c < 4; ++c) {
            const bf16x8 b = *(const bf16x8*)&Ws[(c * 16 + fr) * 40 + fk];
            acc[c] = __builtin_amdgcn_mfma_f32_16x16x32_bf16(a, b, acc[c], 0, 0, 0);
        }
    }
#pragma unroll
    for (int c = 0; c < 4; ++c) {
        const int col = j0 + c * 16 + fr;
        if (col < H4) {
            const float bias = bih[col] + bhh[col];
#pragma unroll
            for (int rg = 0; rg < 4; ++rg) {
                const int row = m0 + wv * 16 + (lane >> 4) * 4 + rg;
                XZ[(size_t)row * H4 + col] = __float2bfloat16(acc[c][rg] + bias);
            }
        }
    }
}

// ---------------------------------------------------------------------------
// Merged recurrence — ROUND-18 structure (verified best, 3341 us) plus ONE
// change: gate ACTIVATIONS folded into the 300-thread reduce phase (tanh for
// gate-2 rows, sigmoid for i/f/o rows) so the critical 75-thread update phase
// does only cc = af*c + ai*ag; hh = ao*tanh(cc) — 1 transcendental instead
// of 5. Round-19's merged-reduce (32 serial LDS reads on 75 threads) is
// REVERTED — it regressed 3341->3622.
// Flag protocol: per-block release flags, depth-2 parity buffer (r18).
// ---------------------------------------------------------------------------
__global__ __launch_bounds__(512, 1) void recur_all(
    const unsigned* __restrict__ WpkL, const unsigned* __restrict__ WpkA,
    const unsigned* __restrict__ WpkI,
    const void* __restrict__ mL, const void* __restrict__ mA, const void* __restrict__ mI,
    const int* __restrict__ modep,
    const int* __restrict__ seqlen,
    const float* __restrict__ wbuf,
    const bf16* __restrict__ xzL, const bf16* __restrict__ xzA, const bf16* __restrict__ xzI,
    float* __restrict__ psumL, float* __restrict__ psumA, float* __restrict__ psumI,
    float* __restrict__ hcL, float* __restrict__ hcA, float* __restrict__ hcI,
    float* __restrict__ hpub,       // [N][2][304]
    unsigned int* __restrict__ flg, // [N][8] slice for THIS chunk, pre-zeroed
    int Tc, int t0)
{
    // ling LDS
    __shared__ float h_s[304];
    __shared__ float c_s[80];
    __shared__ float zp_s[8 * 308];
    __shared__ float zr_s[304];
    __shared__ float wb_s[304];
    // small LDS
    __shared__ __align__(16) float h2_s[128];
    __shared__ __align__(16) float c2_s[128];
    __shared__ __align__(16) float z2_s[512];
    __shared__ float wb2_s[128];
    const int tid = threadIdx.x;
    const int mode = modep[0];

    if (blockIdx.x < 4 * N_) {
        // ================= linguistic =================
        const int xcd = blockIdx.x & 7;
        const int idx = blockIdx.x >> 3;
        const int n = xcd * 8 + (idx >> 2);
        const int b = idx & 3;
        const int hb = 75 * b;
        const int seqn = seqlen[n];

        const int chunk = tid & 7;
        const int rb = tid >> 3;
        const int cjp = chunk * 19;     // packed-col base (19 u32 = 38 cols)
        unsigned w[5][19];
#pragma unroll
        for (int s = 0; s < 5; ++s) {
            const int lr = rb + 64 * s;
            const bool rv = (lr < 300);
            const int gl = rv ? (lr / 75) : 0;
            const int i  = rv ? (lr - gl * 75) : 0;
            const unsigned* wp = WpkL + ((size_t)(gl * 300 + hb + i)) * 150 + cjp;
#pragma unroll
            for (int j = 0; j < 19; ++j) w[s][j] = rv ? wp[j] : 0u;
        }
        int xoff = 0, myg = 0;
        if (tid < 300) {
            myg = tid / 75;
            xoff = myg * 300 + hb + (tid - myg * 75);
        }
        for (int r = tid; r < 304; r += 512) {
            if (t0 == 0 || r >= 300) h_s[r] = 0.0f;
            else h_s[r] = hcL[n * 600 + r];
            wb_s[r] = (r < 300) ? wbuf[r] : 0.0f;
        }
        if (tid < 75) c_s[tid] = (t0 == 0) ? 0.0f : hcL[n * 600 + 300 + hb + tid];
        __syncthreads();

        unsigned int serial = 0;
        unsigned int* const flgn = &flg[n * 8];
        float* const hp = hpub + (size_t)n * 608;

#pragma unroll 1
        for (int tt = 0; tt < Tc; ++tt) {
            const int t = t0 + tt;
            if (t >= seqn) {
                if (b == 0 && tid == 0) psumL[(size_t)n * T_ + t] = 0.0f;
                continue;
            }
            const size_t mbase = (size_t)(n * T_ + t) * 4;
            const bf16* xzt = xzL + ((size_t)((n * Tc + tt) * 4)) * 1200;
#pragma unroll 1
            for (int k = 0; k < 4; ++k) {
                if (!read_mask(mL, mbase + k, mode)) continue;
                const int par = (int)(serial & 1u);
                float a0 = 0.f, a1 = 0.f, a2 = 0.f, a3 = 0.f, a4 = 0.f;
#pragma unroll
                for (int j = 0; j < 19; ++j) {
                    const float2 hv = *(const float2*)&h_s[2 * (cjp + j)];
                    const unsigned u0 = w[0][j], u1 = w[1][j], u2 = w[2][j],
                                   u3 = w[3][j], u4 = w[4][j];
                    a0 += uplo(u0) * hv.x + uphi(u0) * hv.y;
                    a1 += uplo(u1) * hv.x + uphi(u1) * hv.y;
                    a2 += uplo(u2) * hv.x + uphi(u2) * hv.y;
                    a3 += uplo(u3) * hv.x + uphi(u3) * hv.y;
                    a4 += uplo(u4) * hv.x + uphi(u4) * hv.y;
                }
                zp_s[chunk * 308 + rb]       = a0;
                zp_s[chunk * 308 + rb + 64]  = a1;
                zp_s[chunk * 308 + rb + 128] = a2;
                zp_s[chunk * 308 + rb + 192] = a3;
                if (rb < 44) zp_s[chunk * 308 + rb + 256] = a4;
                __syncthreads();   // B1: zp ready
                if (tid < 300) {
                    // reduce + ACTIVATE in parallel across 300 threads
                    float zv = __bfloat162float(xzt[k * 1200 + xoff]);
#pragma unroll
                    for (int c = 0; c < 8; ++c) zv += zp_s[c * 308 + tid];
                    zr_s[tid] = (myg == 2) ? tanhf(zv) : sigf(zv);
                }
                __syncthreads();   // B2: activated values ready
                if (tid < 75) {
                    const float ai = zr_s[tid];
                    const float af = zr_s[75 + tid];
                    const float ag = zr_s[150 + tid];
                    const float ao = zr_s[225 + tid];
                    const float cc = af * c_s[tid] + ai * ag;
                    c_s[tid] = cc;
                    const float hh = ao * tanhf(cc);
                    __hip_atomic_store(&hp[par * 304 + hb + tid], hh,
                                       __ATOMIC_RELAXED, __HIP_MEMORY_SCOPE_AGENT);
                }
                __syncthreads();   // all 75 publishes drained before the flag
                if (tid == 0)
                    __hip_atomic_store(&flgn[b], serial + 1u,
                                       __ATOMIC_RELEASE, __HIP_MEMORY_SCOPE_AGENT);
                if (tid < 4) {     // 4 lanes poll all 4 sibling flags (coalesced)
                    long g = 0;
                    while (__hip_atomic_load(&flgn[tid], __ATOMIC_ACQUIRE,
                                             __HIP_MEMORY_SCOPE_AGENT) < serial + 1u
                           && g < (1L << 22)) { __builtin_amdgcn_s_sleep(1); ++g; }
                }
                __syncthreads();
                if (tid < 300)
                    h_s[tid] = __hip_atomic_load(&hp[par * 304 + tid],
                                                 __ATOMIC_RELAXED, __HIP_MEMORY_SCOPE_AGENT);
                __syncthreads();
                ++serial;
            }
            // fused projection: psumL[n][t] = wbuf[0:300] . h  (fp32)
            if (b == 0 && tid < 64) {
                float v = 0.0f;
                for (int r = tid; r < 300; r += 64) v += wb_s[r] * h_s[r];
#pragma unroll
                for (int off = 32; off; off >>= 1) v += __shfl_down(v, off, 64);
                if (tid == 0) psumL[(size_t)n * T_ + t] = v;
            }
        }
        if (tid < 75) {
            hcL[n * 600 + hb + tid] = h_s[hb + tid];
            hcL[n * 600 + 300 + hb + tid] = c_s[tid];
        }
    } else if (blockIdx.x < 4 * N_ + N_) {
        // ================= image =================
        const int n = blockIdx.x - 4 * N_;
        const int seqn = seqlen[n];
        unsigned w[64];
        {
            const uint4* wp = (const uint4*)(WpkI + (size_t)tid * 64);
#pragma unroll
            for (int jj = 0; jj < 16; ++jj) {
                const uint4 v = wp[jj];
                w[4 * jj] = v.x; w[4 * jj + 1] = v.y; w[4 * jj + 2] = v.z; w[4 * jj + 3] = v.w;
            }
        }
        if (tid < 128) {
            if (t0 == 0) { h2_s[tid] = 0.0f; c2_s[tid] = 0.0f; }
            else { h2_s[tid] = hcI[n * 256 + tid]; c2_s[tid] = hcI[n * 256 + 128 + tid]; }
            wb2_s[tid] = wbuf[364 + tid];
        }
        __syncthreads();
#pragma unroll 1
        for (int tt = 0; tt < Tc; ++tt) {
            const int t = t0 + tt;
            if (t >= seqn) {
                if (tid == 0) psumI[(size_t)n * T_ + t] = 0.0f;
                continue;
            }
            const size_t xbase = ((size_t)((n * Tc + tt) * 4)) * 512;
            const size_t mbase = (size_t)(n * T_ + t) * 4;
#pragma unroll 1
            for (int k = 0; k < 4; ++k) {
                if (!read_mask(mI, mbase + k, mode)) continue;
                float acc = __bfloat162float(xzI[xbase + k * 512 + tid]);
                const float2* hp2 = (const float2*)h2_s;
#pragma unroll
                for (int jj = 0; jj < 64; ++jj) {
                    const float2 hv = hp2[jj];
                    const unsigned u = w[jj];
                    acc += uplo(u) * hv.x + uphi(u) * hv.y;
                }
                z2_s[tid] = acc;
                __syncthreads();
                if (tid < 128) {
                    const float zi = z2_s[tid], zf = z2_s[128 + tid];
                    const float zg = z2_s[256 + tid], zo = z2_s[384 + tid];
                    const float cc = sigf(zf) * c2_s[tid] + sigf(zi) * tanhf(zg);
                    c2_s[tid] = cc;
                    h2_s[tid] = sigf(zo) * tanhf(cc);
                }
                __syncthreads();
            }
            if (tid < 64) {
                float v = wb2_s[tid] * h2_s[tid] + wb2_s[tid + 64] * h2_s[tid + 64];
#pragma unroll
                for (int off = 32; off; off >>= 1) v += __shfl_down(v, off, 64);
                if (tid == 0) psumI[(size_t)n * T_ + t] = v;
            }
        }
        if (tid < 128) { hcI[n * 256 + tid] = h2_s[tid]; hcI[n * 256 + 128 + tid] = c2_s[tid]; }
    } else {
        // ================= acoustic =================
        const int n = blockIdx.x - 5 * N_;
        const int seqn = seqlen[n];
        unsigned w[32];
        if (tid < 256) {
            const uint4* wp = (const uint4*)(WpkA + (size_t)tid * 32);
#pragma unroll
            for (int jj = 0; jj < 8; ++jj) {
                const uint4 v = wp[jj];
                w[4 * jj] = v.x; w[4 * jj + 1] = v.y; w[4 * jj + 2] = v.z; w[4 * jj + 3] = v.w;
            }
        }
        if (tid < 64) {
            if (t0 == 0) { h2_s[tid] = 0.0f; c2_s[tid] = 0.0f; }
            else { h2_s[tid] = hcA[n * 128 + tid]; c2_s[tid] = hcA[n * 128 + 64 + tid]; }
            wb2_s[tid] = wbuf[300 + tid];
        }
        __syncthreads();
#pragma unroll 1
        for (int tt = 0; tt < Tc; ++tt) {
            const int t = t0 + tt;
            if (t >= seqn) {
                if (tid == 0) psumA[(size_t)n * T_ + t] = 0.0f;
                continue;
            }
            const size_t xbase = ((size_t)((n * Tc + tt) * 4)) * 256;
            const size_t mbase = (size_t)(n * T_ + t) * 4;
#pragma unroll 1
            for (int k = 0; k < 4; ++k) {
                if (!read_mask(mA, mbase + k, mode)) continue;
                if (tid < 256) {
                    float acc = __bfloat162float(xzA[xbase + k * 256 + tid]);
                    const float2* hp2 = (const float2*)h2_s;
#pragma unroll
                    for (int jj = 0; jj < 32; ++jj) {
                        const float2 hv = hp2[jj];
                        const unsigned u = w[jj];
                        acc += uplo(u) * hv.x + uphi(u) * hv.y;
                    }
                    z2_s[tid] = acc;
                }
                __syncthreads();
                if (tid < 64) {
                    const float zi = z2_s[tid], zf = z2_s[64 + tid];
                    const float zg = z2_s[128 + tid], zo = z2_s[192 + tid];
                    const float cc = sigf(zf) * c2_s[tid] + sigf(zi) * tanhf(zg);
                    c2_s[tid] = cc;
                    h2_s[tid] = sigf(zo) * tanhf(cc);
                }
                __syncthreads();
            }
            if (tid < 64) {
                float v = wb2_s[tid] * h2_s[tid];
#pragma unroll
                for (int off = 32; off; off >>= 1) v += __shfl_down(v, off, 64);
                if (tid == 0) psumA[(size_t)n * T_ + t] = v;
            }
        }
        if (tid < 64) { hcA[n * 128 + tid] = h2_s[tid]; hcA[n * 128 + 64 + tid] = c2_s[tid]; }
    }
}

// Output: reshape-scramble gather of the three projected scalars.
// fused[i,j] = hs_scan[i*4 + j//64, j%64] -> source (nn=j&63, tt=i*4+(j>>6)).
__global__ void out_combine(const float* __restrict__ wbuf,
                            const float* __restrict__ pL, const float* __restrict__ pA,
                            const float* __restrict__ pI,
                            const float* __restrict__ lmask, float* __restrict__ out)
{
    const int i = blockIdx.x;
    const int j = threadIdx.x;
    const int nn = j & 63;
    const int tt = i * 4 + (j >> 6);
    const size_t src = (size_t)nn * T_ + tt;
    const size_t nt = (size_t)i * T_ + j;
    out[nt] = (pL[src] + pA[src] + pI[src] + wbuf[500]) * lmask[nt];
}

// ---------------------------------------------------------------------------
extern "C" void kernel_launch(void* const* d_in, const int* in_sizes, int n_in,
                              void* d_out, int out_size, void* d_ws, size_t ws_size,
                              hipStream_t stream)
{
    (void)in_sizes; (void)n_in;
    const float* xL   = (const float*)d_in[0];
    const void*  mL   = d_in[1];
    const float* WihL = (const float*)d_in[2];
    const float* WhhL = (const float*)d_in[3];
    const float* bihL = (const float*)d_in[4];
    const float* bhhL = (const float*)d_in[5];
    const float* xA   = (const float*)d_in[6];
    const void*  mA   = d_in[7];
    const float* WihA = (const float*)d_in[8];
    const float* WhhA = (const float*)d_in[9];
    const float* bihA = (const float*)d_in[10];
    const float* bhhA = (const float*)d_in[11];
    const float* xI   = (const float*)d_in[12];
    const void*  mI   = d_in[13];
    const float* WihI = (const float*)d_in[14];
    const float* WhhI = (const float*)d_in[15];
    const float* bihI = (const float*)d_in[16];
    const float* bhhI = (const float*)d_in[17];
    const int*   seqlen = (const int*)d_in[18];
    const float* lmask  = (const float*)d_in[19];
    const float* W1 = (const float*)d_in[20];
    const float* b1 = (const float*)d_in[21];
    const float* W2 = (const float*)d_in[22];
    const float* b2 = (const float*)d_in[23];
    float* out = (float*)d_out;

    // Byte-accurate workspace layout, 64B aligned blocks.
    char* base = (char*)d_ws;
    size_t off = 0;
    auto take = [&](size_t bytes) -> char* {
        char* p = base + off;
        off += (bytes + 63) & ~(size_t)63;
        return p;
    };
    unsigned int* flg = (unsigned int*)take(64 * 512 * sizeof(unsigned int)); // per-chunk [N][8] slices
    int*   modep = (int*)take(64);
    float* wbuf  = (float*)take(512 * sizeof(float));
    float* hcL   = (float*)take((size_t)N_ * 2 * HL * sizeof(float));
    float* hcA   = (float*)take((size_t)N_ * 2 * HA * sizeof(float));
    float* hcI   = (float*)take((size_t)N_ * 2 * HI * sizeof(float));
    float* hpub  = (float*)take((size_t)N_ * 2 * 304 * sizeof(float));
    float* psumL = (float*)take((size_t)N_ * T_ * sizeof(float));
    float* psumA = (float*)take((size_t)N_ * T_ * sizeof(float));
    float* psumI = (float*)take((size_t)N_ * T_ * sizeof(float));
    unsigned short* wpkL = (unsigned short*)take((size_t)H4L * DLP * sizeof(unsigned short));
    unsigned short* wpkA = (unsigned short*)take((size_t)H4A * DAP * sizeof(unsigned short));
    unsigned short* wpkI = (unsigned short*)take((size_t)H4I * DIP * sizeof(unsigned short));
    unsigned* whpL = (unsigned*)take((size_t)1200 * 150 * sizeof(unsigned));
    unsigned* whpA = (unsigned*)take((size_t)256 * 32 * sizeof(unsigned));
    unsigned* whpI = (unsigned*)take((size_t)512 * 64 * sizeof(unsigned));

    // largest t-chunk whose bf16 xz buffers fit in the remaining workspace
    const size_t xz_per_tc = (size_t)N_ * K_ * (H4L + H4A + H4I) * sizeof(bf16);
    int Tc = T_;
    while (Tc > 1 && off + (size_t)Tc * xz_per_tc + 256 > ws_size) Tc >>= 1;
    if (off + (size_t)Tc * xz_per_tc + 256 > ws_size) {
        hipMemsetAsync(d_out, 0, (size_t)out_size * sizeof(float), stream);
        return;
    }
    if (Tc > 64) Tc = 64;   // flg slices sized for <=64 chunks
    bf16* xzL = (bf16*)take((size_t)N_ * Tc * K_ * H4L * sizeof(bf16));
    bf16* xzA = (bf16*)take((size_t)N_ * Tc * K_ * H4A * sizeof(bf16));
    bf16* xzI = (bf16*)take((size_t)N_ * Tc * K_ * H4I * sizeof(bf16));

    const int nchunks = T_ / Tc;
    hipMemsetAsync(flg, 0, (size_t)nchunks * 512 * sizeof(unsigned int), stream);
    mask_mode_detect<<<1, 256, 0, stream>>>((const unsigned int*)mL, modep);
    wprep<<<1, 512, 0, stream>>>(W1, b1, W2, b2, wbuf);
    prep_w3<<<(H4L * DLP + 255) / 256, 256, 0, stream>>>(WihL, WihA, WihI, wpkL, wpkA, wpkI);
    prep_whh<<<(1200 * 150 + 255) / 256, 256, 0, stream>>>(WhhL, WhhA, WhhI, whpL, whpA, whpI);

    const int My = (N_ * Tc * K_) / 64;
    for (int c = 0; c < nchunks; ++c) {
        const int t0 = c * Tc;
        gemm_xz3<<<dim3((H4L + 63) / 64, My, 3), 256, 0, stream>>>(
            xL, wpkL, bihL, bhhL, xzL,
            xA, wpkA, bihA, bhhA, xzA,
            xI, wpkI, bihI, bhhI, xzI,
            seqlen, Tc, t0);
        recur_all<<<6 * N_, 512, 0, stream>>>(
            whpL, whpA, whpI, mL, mA, mI, modep, seqlen, wbuf,
            xzL, xzA, xzI, psumL, psumA, psumI,
            hcL, hcA, hcI, hpub, flg + (size_t)c * 512, Tc, t0);
    }
    out_combine<<<N_, T_, 0, stream>>>(wbuf, psumL, psumA, psumI, lmask, out);
}